// Round 7
// baseline (162.691 us; speedup 1.0000x reference)
//
#include <hip/hip_runtime.h>

typedef short bf16x8 __attribute__((ext_vector_type(8)));
typedef short bf16x4 __attribute__((ext_vector_type(4)));
typedef float f32x4 __attribute__((ext_vector_type(4)));

__device__ __forceinline__ unsigned short f2bf(float f) {
    unsigned int u = __float_as_uint(f);
    unsigned int r = u + 0x7FFFu + ((u >> 16) & 1u);
    return (unsigned short)(r >> 16);
}

// pack two f32 -> one u32 of 2 bf16 (lo = a, hi = b)
__device__ __forceinline__ unsigned pkbf(float a, float b) {
    unsigned r;
    asm volatile("v_cvt_pk_bf16_f32 %0, %1, %2" : "=v"(r) : "v"(a), "v"(b));
    return r;
}

// K=16 bf16 MFMA (A,B = 4 bf16 / 2 VGPRs per lane)
__device__ __forceinline__ f32x4 mfma16(bf16x4 a, bf16x4 b, f32x4 c) {
#if __has_builtin(__builtin_amdgcn_mfma_f32_16x16x16bf16_1k)
    return __builtin_amdgcn_mfma_f32_16x16x16bf16_1k(a, b, c, 0, 0, 0);
#elif __has_builtin(__builtin_amdgcn_mfma_f32_16x16x16_bf16)
    return __builtin_amdgcn_mfma_f32_16x16x16_bf16(a, b, c, 0, 0, 0);
#else
    asm volatile("v_mfma_f32_16x16x16_bf16 %0, %1, %2, %0" : "+v"(c) : "v"(a), "v"(b));
    return c;
#endif
}

// ---------------- weight prep ----------------
// x32 frag layout: idx = ((nt*KS + ks)*64 + lane)*8 + e -> W[k = ks*32 + (lane>>4)*8 + e][n = nt*16 + (lane&15)]
// bW3f16 (K=16 B-frag, at ws+53248): idx2 = (s*64 + lane)*4 + e -> W3[16s + 4*(lane>>4) + e][lane&15]
__global__ __launch_bounds__(256) void prep_all(
        const float* __restrict__ uW1, const float* __restrict__ uW2, const float* __restrict__ uW3,
        const float* __restrict__ bW1, const float* __restrict__ bW2, const float* __restrict__ bW3,
        unsigned short* __restrict__ ws) {
    int idx = blockIdx.x * 256 + threadIdx.x;
    if (idx >= 53248) {
        if (idx < 55296) {
            int li = idx - 53248;
            int e = li & 3, l = (li >> 2) & 63, s = li >> 8;
            int k = 16 * s + 4 * (l >> 4) + e, n = l & 15;
            float v = (n < 6) ? bW3[k * 6 + n] : 0.f;
            ws[53248 + li] = f2bf(v);
        }
        return;
    }
    const float* W; int Ksrc, Nsrc, ntsh; unsigned short* dst; int li;
    if (idx < 8192)       { W = uW1; Ksrc = 38;  Nsrc = 128; ntsh = 10; dst = ws;         li = idx; }
    else if (idx < 16384) { W = bW1; Ksrc = 44;  Nsrc = 128; ntsh = 10; dst = ws + 8192;  li = idx - 8192; }
    else if (idx < 32768) { W = uW2; Ksrc = 128; Nsrc = 128; ntsh = 11; dst = ws + 16384; li = idx - 16384; }
    else if (idx < 49152) { W = bW2; Ksrc = 128; Nsrc = 128; ntsh = 11; dst = ws + 32768; li = idx - 32768; }
    else if (idx < 51200) { W = uW3; Ksrc = 128; Nsrc = 6;   ntsh = 11; dst = ws + 49152; li = idx - 49152; }
    else                  { W = bW3; Ksrc = 128; Nsrc = 6;   ntsh = 11; dst = ws + 51200; li = idx - 51200; }
    int e  = li & 7;
    int l  = (li >> 3) & 63;
    int KS = (ntsh == 10) ? 2 : 4;
    int ks = (li >> 9) & (KS - 1);
    int nt = li >> ntsh;
    int k  = ks * 32 + (l >> 4) * 8 + e;
    int n  = nt * 16 + (l & 15);
    float v = (k < Ksrc && n < Nsrc) ? W[k * Nsrc + n] : 0.0f;
    dst[li] = f2bf(v);
}

// ---------------- unary kernel (unchanged, verified) ----------------
__global__ __launch_bounds__(256, 3) void unary_kernel(
        const float* __restrict__ config, const float* __restrict__ action,
        const unsigned short* __restrict__ W1f, const float* __restrict__ b1,
        const unsigned short* __restrict__ W2f, const float* __restrict__ b2,
        const unsigned short* __restrict__ W3f, const float* __restrict__ b3,
        float* __restrict__ out) {
    __shared__ __align__(16) unsigned char smem[4 * 8192];
    const int tid = threadIdx.x;
    const int w = tid >> 6;
    const int l = tid & 63;
    const int g = l >> 4;
    const int c = l & 15;
    unsigned char* buf = smem + w * 8192;

    {
        const int rowL = l >> 1;
        const int kh   = l & 1;
        const int sw   = (rowL & 7) << 4;
        const int base = rowL * 128 + kh * 64;
        const int rg = blockIdx.x * 128 + w * 32 + rowL;
        const int b = rg >> 4;
        const int i = rg & 15;
        const float* cbr = config + b * 96 + i * 6;
        const float* ab  = action + b * 32;
        if (kh == 0) {
            float ov[6];
            { const float2 t0 = *(const float2*)(cbr);
              const float2 t1 = *(const float2*)(cbr + 2);
              const float2 t2 = *(const float2*)(cbr + 4);
              ov[0]=t0.x; ov[1]=t0.y; ov[2]=t1.x; ov[3]=t1.y; ov[4]=t2.x; ov[5]=t2.y; }
            float av[26];
            #pragma unroll
            for (int q = 0; q < 6; ++q) {
                const float4 t = *(const float4*)(ab + 4 * q);
                av[4*q]=t.x; av[4*q+1]=t.y; av[4*q+2]=t.z; av[4*q+3]=t.w;
            }
            { const float2 t = *(const float2*)(ab + 24); av[24]=t.x; av[25]=t.y; }
            #pragma unroll
            for (int ch = 0; ch < 4; ++ch) {
                float x[8];
                #pragma unroll
                for (int t8 = 0; t8 < 8; ++t8) {
                    const int k = ch * 8 + t8;
                    x[t8] = (k < 6) ? ov[k] : av[k - 6];
                }
                union { unsigned uu[4]; bf16x8 v; } U;
                U.uu[0] = pkbf(x[0], x[1]); U.uu[1] = pkbf(x[2], x[3]);
                U.uu[2] = pkbf(x[4], x[5]); U.uu[3] = pkbf(x[6], x[7]);
                *(bf16x8*)(buf + ((base + ch * 16) ^ sw)) = U.v;
            }
        } else {
            float av2[6];
            { const float2 t = *(const float2*)(ab + 26); av2[0]=t.x; av2[1]=t.y; }
            { const float4 t = *(const float4*)(ab + 28); av2[2]=t.x; av2[3]=t.y; av2[4]=t.z; av2[5]=t.w; }
            {
                union { unsigned uu[4]; bf16x8 v; } U;
                U.uu[0] = pkbf(av2[0], av2[1]); U.uu[1] = pkbf(av2[2], av2[3]);
                U.uu[2] = pkbf(av2[4], av2[5]); U.uu[3] = 0u;
                *(bf16x8*)(buf + ((base + 0) ^ sw)) = U.v;
            }
            const bf16x8 z = {0,0,0,0,0,0,0,0};
            *(bf16x8*)(buf + ((base + 16) ^ sw)) = z;
            *(bf16x8*)(buf + ((base + 32) ^ sw)) = z;
            *(bf16x8*)(buf + ((base + 48) ^ sw)) = z;
        }
    }
    __syncthreads();

    const f32x4 zero4 = {0.f, 0.f, 0.f, 0.f};

    bf16x8 xf[2][2];
    #pragma unroll
    for (int mt = 0; mt < 2; ++mt)
        #pragma unroll
        for (int ks = 0; ks < 2; ++ks) {
            const int row = mt * 16 + c;
            xf[mt][ks] = *(const bf16x8*)(buf + ((row * 128 + ks * 64 + g * 16) ^ ((c & 7) << 4)));
        }

    // GEMM1
    #pragma unroll
    for (int nh = 0; nh < 2; ++nh) {
        f32x4 acc[2][4];
        #pragma unroll
        for (int mt = 0; mt < 2; ++mt)
            #pragma unroll
            for (int ntl = 0; ntl < 4; ++ntl) acc[mt][ntl] = zero4;
        #pragma unroll
        for (int ntl = 0; ntl < 4; ++ntl) {
            const int nt = nh * 4 + ntl;
            #pragma unroll
            for (int ks = 0; ks < 2; ++ks) {
                const bf16x8 bfr = *(const bf16x8*)(W1f + ((nt * 2 + ks) * 64 + l) * 8);
                #pragma unroll
                for (int mt = 0; mt < 2; ++mt)
                    acc[mt][ntl] = __builtin_amdgcn_mfma_f32_16x16x32_bf16(xf[mt][ks], bfr, acc[mt][ntl], 0, 0, 0);
            }
        }
        #pragma unroll
        for (int ntl = 0; ntl < 4; ++ntl) {
            const int col = (nh * 4 + ntl) * 16 + c;
            const float bias = b1[col];
            #pragma unroll
            for (int mt = 0; mt < 2; ++mt)
                #pragma unroll
                for (int r = 0; r < 4; ++r) {
                    const int row = mt * 16 + g * 4 + r;
                    const float hv = fmaxf(acc[mt][ntl][r] + bias, 0.f);
                    *(unsigned short*)(buf + ((row * 256 + col * 2) ^ ((row & 7) << 4))) = f2bf(hv);
                }
        }
    }
    __syncthreads();

    bf16x8 hf[2][4];
    #pragma unroll
    for (int mt = 0; mt < 2; ++mt)
        #pragma unroll
        for (int ks = 0; ks < 4; ++ks) {
            const int row = mt * 16 + c;
            hf[mt][ks] = *(const bf16x8*)(buf + ((row * 256 + ks * 64 + g * 16) ^ ((c & 7) << 4)));
        }

    // GEMM2
    #pragma unroll
    for (int nh = 0; nh < 2; ++nh) {
        f32x4 acc[2][4];
        #pragma unroll
        for (int mt = 0; mt < 2; ++mt)
            #pragma unroll
            for (int ntl = 0; ntl < 4; ++ntl) acc[mt][ntl] = zero4;
        #pragma unroll
        for (int ntl = 0; ntl < 4; ++ntl) {
            const int nt = nh * 4 + ntl;
            #pragma unroll
            for (int ks = 0; ks < 4; ++ks) {
                const bf16x8 bfr = *(const bf16x8*)(W2f + ((nt * 4 + ks) * 64 + l) * 8);
                #pragma unroll
                for (int mt = 0; mt < 2; ++mt)
                    acc[mt][ntl] = __builtin_amdgcn_mfma_f32_16x16x32_bf16(hf[mt][ks], bfr, acc[mt][ntl], 0, 0, 0);
            }
        }
        #pragma unroll
        for (int ntl = 0; ntl < 4; ++ntl) {
            const int col = (nh * 4 + ntl) * 16 + c;
            const float bias = b2[col];
            #pragma unroll
            for (int mt = 0; mt < 2; ++mt)
                #pragma unroll
                for (int r = 0; r < 4; ++r) {
                    const int row = mt * 16 + g * 4 + r;
                    const float hv = fmaxf(acc[mt][ntl][r] + bias, 0.f);
                    *(unsigned short*)(buf + ((row * 256 + col * 2) ^ ((row & 7) << 4))) = f2bf(hv);
                }
        }
    }
    __syncthreads();

    bf16x8 h2f[2][4];
    #pragma unroll
    for (int mt = 0; mt < 2; ++mt)
        #pragma unroll
        for (int ks = 0; ks < 4; ++ks) {
            const int row = mt * 16 + c;
            h2f[mt][ks] = *(const bf16x8*)(buf + ((row * 256 + ks * 64 + g * 16) ^ ((c & 7) << 4)));
        }

    // GEMM3
    f32x4 acc3[2];
    acc3[0] = zero4; acc3[1] = zero4;
    #pragma unroll
    for (int ks = 0; ks < 4; ++ks) {
        const bf16x8 bfr = *(const bf16x8*)(W3f + (ks * 64 + l) * 8);
        #pragma unroll
        for (int mt = 0; mt < 2; ++mt)
            acc3[mt] = __builtin_amdgcn_mfma_f32_16x16x32_bf16(h2f[mt][ks], bfr, acc3[mt], 0, 0, 0);
    }

    const int rgbase = blockIdx.x * 128 + w * 32;
    const float b3v = (c < 6) ? b3[c] : 0.f;
    #pragma unroll
    for (int mt = 0; mt < 2; ++mt)
        #pragma unroll
        for (int r = 0; r < 4; ++r) {
            const int rg = rgbase + mt * 16 + g * 4 + r;
            const int b = rg >> 4, i = rg & 15;
            if (c < 6) {
                const int idx = b * 96 + i * 6 + c;
                out[idx] = acc3[mt][r] + b3v + config[idx];
            }
        }
}

// ---------------- binary kernel v5: LDS-free chunk loop via K=16 GEMM3 ----------------
// grid 8192: b = blk>>1, h = blk&1. Block covers i in [8h, 8h+8), all j.
// PQ: rows 0-7 = P' (block-local i'), rows 8-23 = Q[j].
// a2 (swapped-GEMM2 C) doubles as the K=16 A-fragment of H2 -> GEMM3 needs NO LDS.
__global__ __launch_bounds__(256, 4) void binary_kernel(
        const float* __restrict__ config, const float* __restrict__ action,
        const unsigned short* __restrict__ W1f, const float* __restrict__ b1,
        const unsigned short* __restrict__ W2f, const float* __restrict__ b2,
        const unsigned short* __restrict__ W3s, const float* __restrict__ b3,
        float* __restrict__ out) {
    __shared__ __align__(16) unsigned char PQs[12288];   // 24 rows x 128 f32, swizzled

    const int tid = threadIdx.x;
    const int w = tid >> 6, l = tid & 63, g = l >> 4, c = l & 15;
    const int b = blockIdx.x >> 1, h = blockIdx.x & 1;
    const float* cb = config + b * 96;
    const float* ab = action + b * 32;
    const f32x4 zero4 = {0.f, 0.f, 0.f, 0.f};

    // ---- preload phase-1 weights + bias (overlaps T-build global loads) ----
    bf16x8 wf1[2][2];
    #pragma unroll
    for (int mt1 = 0; mt1 < 2; ++mt1)
        #pragma unroll
        for (int ksp = 0; ksp < 2; ++ksp)
            wf1[mt1][ksp] = *(const bf16x8*)(W1f + (((2 * w + mt1) * 2 + ksp) * 64 + l) * 8);
    f32x4 b1v[2];
    b1v[0] = *(const f32x4*)(b1 + 32 * w + 4 * g);
    b1v[1] = *(const f32x4*)(b1 + 32 * w + 16 + 4 * g);
    const float b3v = (c < 6) ? b3[c] : 0.f;

    // ---- T-fragments in registers (element e -> k = 32*ks + 8*g + e) ----
    bf16x8 tP0, tP1, tQ0;
    {
        const bf16x8 z8 = {0,0,0,0,0,0,0,0};
        tP0 = z8; tP1 = z8; tQ0 = z8;
        union { unsigned u[4]; bf16x8 v; } U;
        if (g == 0) {
            const float* obp = cb + (8 * h + (c & 7)) * 6;
            const float2 a0 = *(const float2*)obp, a1 = *(const float2*)(obp + 2), a2v = *(const float2*)(obp + 4);
            U.u[0] = pkbf(a0.x, a0.y); U.u[1] = pkbf(a1.x, a1.y); U.u[2] = pkbf(a2v.x, a2v.y); U.u[3] = 0u;
            tP0 = U.v;                                   // k 0..5 = obj_i
            const float4 b0 = *(const float4*)(ab + 20), b1q = *(const float4*)(ab + 24);
            U.u[0] = pkbf(b0.x, b0.y); U.u[1] = pkbf(b0.z, b0.w);
            U.u[2] = pkbf(b1q.x, b1q.y); U.u[3] = pkbf(b1q.z, b1q.w);
            tP1 = U.v;                                   // k 32..39 = action[20..27]
            const float2 q0 = *(const float2*)(cb + c * 6);
            U.u[0] = 0u; U.u[1] = 0u; U.u[2] = 0u; U.u[3] = pkbf(q0.x, q0.y);
            tQ0 = U.v;                                   // k 6,7 = obj_j[0,1]
        } else if (g == 1) {
            const float4 b0 = *(const float4*)(ab + 0);
            U.u[0] = 0u; U.u[1] = 0u; U.u[2] = pkbf(b0.x, b0.y); U.u[3] = pkbf(b0.z, b0.w);
            tP0 = U.v;                                   // k 12..15 = action[0..3]
            const float4 b1q = *(const float4*)(ab + 28);
            U.u[0] = pkbf(b1q.x, b1q.y); U.u[1] = pkbf(b1q.z, b1q.w); U.u[2] = 0u; U.u[3] = 0u;
            tP1 = U.v;                                   // k 40..43 = action[28..31]
            const float* obq = cb + c * 6;
            const float2 q1 = *(const float2*)(obq + 2), q2 = *(const float2*)(obq + 4);
            U.u[0] = pkbf(q1.x, q1.y); U.u[1] = pkbf(q2.x, q2.y); U.u[2] = 0u; U.u[3] = 0u;
            tQ0 = U.v;                                   // k 8..11 = obj_j[2..5]
        } else if (g == 2) {
            const float4 b0 = *(const float4*)(ab + 4), b1q = *(const float4*)(ab + 8);
            U.u[0] = pkbf(b0.x, b0.y); U.u[1] = pkbf(b0.z, b0.w);
            U.u[2] = pkbf(b1q.x, b1q.y); U.u[3] = pkbf(b1q.z, b1q.w);
            tP0 = U.v;                                   // k 16..23 = action[4..11]
        } else {
            const float4 b0 = *(const float4*)(ab + 12), b1q = *(const float4*)(ab + 16);
            U.u[0] = pkbf(b0.x, b0.y); U.u[1] = pkbf(b0.z, b0.w);
            U.u[2] = pkbf(b1q.x, b1q.y); U.u[3] = pkbf(b1q.z, b1q.w);
            tP0 = U.v;                                   // k 24..31 = action[12..19]
        }
    }

    // ---- phase 1 (swapped): PQ^T = W1^T @ T^T; bias via acc init; 6 MFMAs ----
    {
        f32x4 acc1[2][2];
        acc1[0][0] = b1v[0]; acc1[0][1] = zero4;   // P rows get bias, Q rows don't
        acc1[1][0] = b1v[1]; acc1[1][1] = zero4;
        #pragma unroll
        for (int mt1 = 0; mt1 < 2; ++mt1) {
            acc1[mt1][0] = __builtin_amdgcn_mfma_f32_16x16x32_bf16(wf1[mt1][0], tP0, acc1[mt1][0], 0, 0, 0);
            acc1[mt1][0] = __builtin_amdgcn_mfma_f32_16x16x32_bf16(wf1[mt1][1], tP1, acc1[mt1][0], 0, 0, 0);
            acc1[mt1][1] = __builtin_amdgcn_mfma_f32_16x16x32_bf16(wf1[mt1][0], tQ0, acc1[mt1][1], 0, 0, 0);
        }
        #pragma unroll
        for (int mt1 = 0; mt1 < 2; ++mt1) {
            const int fb = (32 * w + 16 * mt1 + 4 * g) * 4;
            if (c < 8) {                        // P rows: block-local i' = c
                float2 v0; v0.x = acc1[mt1][0][0]; v0.y = acc1[mt1][0][1];
                float2 v1; v1.x = acc1[mt1][0][2]; v1.y = acc1[mt1][0][3];
                *(float2*)(PQs + ((c * 512 + fb)     ^ ((c & 7) << 4))) = v0;
                *(float2*)(PQs + ((c * 512 + fb + 8) ^ ((c & 7) << 4))) = v1;
            }
            {                                   // Q rows at 8 + j
                const int row = 8 + c;
                float2 v0; v0.x = acc1[mt1][1][0]; v0.y = acc1[mt1][1][1];
                float2 v1; v1.x = acc1[mt1][1][2]; v1.y = acc1[mt1][1][3];
                *(float2*)(PQs + ((row * 512 + fb)     ^ ((c & 7) << 4))) = v0;
                *(float2*)(PQs + ((row * 512 + fb + 8) ^ ((c & 7) << 4))) = v1;
            }
        }
    }
    __syncthreads();

    // ---- phase 2: H1 B-fragments: relu(P'[i'] + Q[c]); Q hoisted out of nt loop ----
    const int i0 = h * 8 + 2 * w;               // global i base for this wave
    bf16x8 h1f[2][4];
    #pragma unroll
    for (int ks = 0; ks < 4; ++ks) {
        const int kb = (32 * ks + 8 * g) * 4;
        const f32x4 q0 = *(const f32x4*)(PQs + (((8 + c) * 512 + kb) ^ ((c & 7) << 4)));
        const f32x4 q1 = *(const f32x4*)(PQs + (((8 + c) * 512 + kb + 16) ^ ((c & 7) << 4)));
        #pragma unroll
        for (int nt = 0; nt < 2; ++nt) {
            const int ip = 2 * w + nt;          // block-local P row (broadcast read)
            const f32x4 p0 = *(const f32x4*)(PQs + ((ip * 512 + kb) ^ ((ip & 7) << 4)));
            const f32x4 p1 = *(const f32x4*)(PQs + ((ip * 512 + kb + 16) ^ ((ip & 7) << 4)));
            union { unsigned u[4]; bf16x8 v; } un;
            un.u[0] = pkbf(fmaxf(p0[0] + q0[0], 0.f), fmaxf(p0[1] + q0[1], 0.f));
            un.u[1] = pkbf(fmaxf(p0[2] + q0[2], 0.f), fmaxf(p0[3] + q0[3], 0.f));
            un.u[2] = pkbf(fmaxf(p1[0] + q1[0], 0.f), fmaxf(p1[1] + q1[1], 0.f));
            un.u[3] = pkbf(fmaxf(p1[2] + q1[2], 0.f), fmaxf(p1[3] + q1[3], 0.f));
            h1f[nt][ks] = un.v;
        }
    }

    // ---- phases 3-5, kappa-chunked, LDS-free: GEMM2 -> pack -> K=16 GEMM3 in registers ----
    f32x4 acc3[2];
    acc3[0][0] = b3v; acc3[0][1] = b3v; acc3[0][2] = b3v; acc3[0][3] = b3v;
    acc3[1] = acc3[0];
    #pragma unroll
    for (int ks = 0; ks < 4; ++ks) {
        // --- issue ALL loads for this chunk, then pin them before the MFMAs ---
        bf16x8 wfa[8];
        #pragma unroll
        for (int q = 0; q < 8; ++q)   // q = mt1*4 + ksp
            wfa[q] = *(const bf16x8*)(W2f + (((2 * ks + (q >> 2)) * 4 + (q & 3)) * 64 + l) * 8);
        union { uint2 u2; bf16x4 v; } w3b[2];
        w3b[0].u2 = *(const uint2*)(W3s + ((2 * ks)     * 64 + l) * 4);
        w3b[1].u2 = *(const uint2*)(W3s + ((2 * ks + 1) * 64 + l) * 4);
        const f32x4 bv0 = *(const f32x4*)(b2 + 32 * ks + 4 * g);
        const f32x4 bv1 = *(const f32x4*)(b2 + 32 * ks + 16 + 4 * g);
        __builtin_amdgcn_sched_barrier(0);

        f32x4 a2[2][2];
        a2[0][0] = bv0; a2[0][1] = bv0;   // bias in accumulator init
        a2[1][0] = bv1; a2[1][1] = bv1;
        #pragma unroll
        for (int ksp = 0; ksp < 4; ++ksp) {
            #pragma unroll
            for (int mt1 = 0; mt1 < 2; ++mt1) {
                a2[mt1][0] = __builtin_amdgcn_mfma_f32_16x16x32_bf16(wfa[mt1 * 4 + ksp], h1f[0][ksp], a2[mt1][0], 0, 0, 0);
                a2[mt1][1] = __builtin_amdgcn_mfma_f32_16x16x32_bf16(wfa[mt1 * 4 + ksp], h1f[1][ksp], a2[mt1][1], 0, 0, 0);
            }
        }
        // pack (relu) -> a2 IS the K=16 A-frag of H2: acc3[nt] += H2_slice @ W3_slice
        #pragma unroll
        for (int mt1 = 0; mt1 < 2; ++mt1) {
            #pragma unroll
            for (int nt = 0; nt < 2; ++nt) {
                union { unsigned u[2]; bf16x4 v; } pa;
                pa.u[0] = pkbf(fmaxf(a2[mt1][nt][0], 0.f), fmaxf(a2[mt1][nt][1], 0.f));
                pa.u[1] = pkbf(fmaxf(a2[mt1][nt][2], 0.f), fmaxf(a2[mt1][nt][3], 0.f));
                acc3[nt] = mfma16(pa.v, w3b[mt1].v, acc3[nt]);
            }
        }
    }

    // ---- phase 6: mask diagonal (j = 4g+r), sum over j, accumulate into out ----
    #pragma unroll
    for (int nt = 0; nt < 2; ++nt) {
        const int i = i0 + nt;
        float s = 0.f;
        #pragma unroll
        for (int r = 0; r < 4; ++r) {
            const int j = 4 * g + r;
            if (j != i) s += acc3[nt][r];      // b3 already in accumulator
        }
        s += __shfl_xor(s, 16, 64);
        s += __shfl_xor(s, 32, 64);
        if (g == 0 && c < 6) out[b * 96 + i * 6 + c] += s;
    }
}

extern "C" void kernel_launch(void* const* d_in, const int* in_sizes, int n_in,
                              void* d_out, int out_size, void* d_ws, size_t ws_size,
                              hipStream_t stream) {
    const float* config = (const float*)d_in[0];
    const float* action = (const float*)d_in[1];
    const float* uW1 = (const float*)d_in[2];
    const float* ub1 = (const float*)d_in[3];
    const float* uW2 = (const float*)d_in[4];
    const float* ub2 = (const float*)d_in[5];
    const float* uW3 = (const float*)d_in[6];
    const float* ub3 = (const float*)d_in[7];
    const float* bW1 = (const float*)d_in[8];
    const float* bb1 = (const float*)d_in[9];
    const float* bW2 = (const float*)d_in[10];
    const float* bb2 = (const float*)d_in[11];
    const float* bW3 = (const float*)d_in[12];
    const float* bb3 = (const float*)d_in[13];
    float* out = (float*)d_out;

    unsigned short* ws   = (unsigned short*)d_ws;
    unsigned short* uW1f = ws;            // 8192 elems
    unsigned short* bW1f = ws + 8192;     // 8192
    unsigned short* uW2f = ws + 16384;    // 16384
    unsigned short* bW2f = ws + 32768;    // 16384
    unsigned short* uW3f = ws + 49152;    // 2048
    // ws + 51200: bW3 x32 layout (2048, unused by binary v5 but still prepped)
    unsigned short* bW3s = ws + 53248;    // 2048 (K=16 B-frag layout)

    prep_all<<<216, 256, 0, stream>>>(uW1, uW2, uW3, bW1, bW2, bW3, ws);
    // unary first: writes out = objs + u_out (every element exactly once)
    unary_kernel<<<512, 256, 0, stream>>>(config, action, uW1f, ub1, uW2f, ub2, uW3f, ub3, out);
    // binary second: out += b_sum (stream-ordered after unary)
    binary_kernel<<<8192, 256, 0, stream>>>(config, action, bW1f, bb1, bW2f, bb2, bW3s, bb3, out);
}

// Round 8
// 148.753 us; speedup vs baseline: 1.0937x; 1.0937x over previous
//
#include <hip/hip_runtime.h>

typedef short bf16x8 __attribute__((ext_vector_type(8)));
typedef short bf16x4 __attribute__((ext_vector_type(4)));
typedef float f32x4 __attribute__((ext_vector_type(4)));

__device__ __forceinline__ unsigned short f2bf(float f) {
    unsigned int u = __float_as_uint(f);
    unsigned int r = u + 0x7FFFu + ((u >> 16) & 1u);
    return (unsigned short)(r >> 16);
}

// pack two f32 -> one u32 of 2 bf16 (lo = a, hi = b)
__device__ __forceinline__ unsigned pkbf(float a, float b) {
    unsigned r;
    asm volatile("v_cvt_pk_bf16_f32 %0, %1, %2" : "=v"(r) : "v"(a), "v"(b));
    return r;
}

// K=16 bf16 MFMA (A,B = 4 bf16 / 2 VGPRs per lane)  [verified in r7: passed absmax 0.25]
__device__ __forceinline__ f32x4 mfma16(bf16x4 a, bf16x4 b, f32x4 c) {
#if __has_builtin(__builtin_amdgcn_mfma_f32_16x16x16bf16_1k)
    return __builtin_amdgcn_mfma_f32_16x16x16bf16_1k(a, b, c, 0, 0, 0);
#elif __has_builtin(__builtin_amdgcn_mfma_f32_16x16x16_bf16)
    return __builtin_amdgcn_mfma_f32_16x16x16_bf16(a, b, c, 0, 0, 0);
#else
    asm volatile("v_mfma_f32_16x16x16_bf16 %0, %1, %2, %0" : "+v"(c) : "v"(a), "v"(b));
    return c;
#endif
}

// ---------------- weight prep ----------------
// ws layout (elems):
//   [0,8192)      bW1f  : binary W1 x32-frags (44->64 pad x 128), KS=2
//   [8192,16384)  uW1f44: unary W1 remapped into the 44-dim slot layout (k<6 -> uW1[k],
//                         12<=k<44 -> uW1[k-6], else 0) then x32-frags, KS=2
//   [16384,32768) bW2f  : x32-frags 128x128, KS=4
//   [32768,49152) uW2f  : x32-frags 128x128, KS=4
//   [49152,51200) bW3s  : K=16 B-frags: idx=(s*64+l)*4+e -> W3[16s+4*(l>>4)+e][l&15]
//   [51200,53248) uW3s  : same for uW3
__global__ __launch_bounds__(256) void prep_all(
        const float* __restrict__ uW1, const float* __restrict__ uW2, const float* __restrict__ uW3,
        const float* __restrict__ bW1, const float* __restrict__ bW2, const float* __restrict__ bW3,
        unsigned short* __restrict__ ws) {
    int idx = blockIdx.x * 256 + threadIdx.x;
    if (idx >= 53248) return;
    if (idx >= 49152) {
        const float* W = (idx < 51200) ? bW3 : uW3;
        int li = (idx - 49152) & 2047;
        int e = li & 3, l = (li >> 2) & 63, s = li >> 8;
        int k = 16 * s + 4 * (l >> 4) + e, n = l & 15;
        ws[idx] = f2bf((n < 6) ? W[k * 6 + n] : 0.f);
        return;
    }
    int seg, li; const float* W; int KS;
    if (idx < 8192)       { seg = 0; li = idx;         W = bW1; KS = 2; }
    else if (idx < 16384) { seg = 1; li = idx - 8192;  W = uW1; KS = 2; }
    else if (idx < 32768) { seg = 2; li = idx - 16384; W = bW2; KS = 4; }
    else                  { seg = 3; li = idx - 32768; W = uW2; KS = 4; }
    int e = li & 7, l = (li >> 3) & 63;
    int ks = (li >> 9) & (KS - 1);
    int nt = li >> ((KS == 2) ? 10 : 11);
    int k = 32 * ks + 8 * (l >> 4) + e;
    int n = 16 * nt + (l & 15);
    float v;
    if (seg == 0)      v = (k < 44) ? W[k * 128 + n] : 0.f;
    else if (seg == 1) { int ksrc = (k < 6) ? k : (k >= 12 && k < 44) ? (k - 6) : -1;
                         v = (ksrc >= 0) ? W[ksrc * 128 + n] : 0.f; }
    else               v = W[k * 128 + n];
    ws[idx] = f2bf(v);
}

// ---------------- fused kernel: unary + binary, one block per sample ----------------
// grid 4096 (b = blockIdx.x), 256 threads (4 waves). Wave w owns i = 4w..4w+3 (x 16 j).
// PQs rows 0-15 = P'[i] (b1 in), rows 16-31 = Q[j]. Pus rows 0-15 = P_u[i] (ub1 in).
// W2s = staged copy of bW2f frag array. Psum = per-wave unary partial out (kappa-split).
__global__ __launch_bounds__(256, 2) void fused_kernel(
        const float* __restrict__ config, const float* __restrict__ action,
        const unsigned short* __restrict__ bW1f, const float* __restrict__ bb1,
        const unsigned short* __restrict__ uW1f, const float* __restrict__ ub1,
        const unsigned short* __restrict__ bW2f, const float* __restrict__ bb2,
        const unsigned short* __restrict__ uW2f, const float* __restrict__ ub2,
        const unsigned short* __restrict__ bW3s, const float* __restrict__ bb3,
        const unsigned short* __restrict__ uW3s, const float* __restrict__ ub3,
        float* __restrict__ out) {
    __shared__ __align__(16) unsigned char PQs[16384];
    __shared__ __align__(16) unsigned char Pus[8192];
    __shared__ __align__(16) unsigned char W2s[32768];
    __shared__ __align__(16) float Psum[1024];

    const int tid = threadIdx.x;
    const int w = tid >> 6, l = tid & 63, g = l >> 4, c = l & 15;
    const int b = blockIdx.x;
    const float* cb = config + b * 96;
    const float* ab = action + b * 32;
    const f32x4 zero4 = {0.f, 0.f, 0.f, 0.f};

    // ---- issue W2 stage loads early (latency hidden under T-build + phase 1) ----
    uint4 stg[8];
    {
        const uint4* s4 = (const uint4*)bW2f;
        #pragma unroll
        for (int it = 0; it < 8; ++it) stg[it] = s4[tid + 256 * it];
    }

    // ---- preload phase-1 weights (binary + unary) and biases ----
    bf16x8 wfb[2][2], wfu[2][2];
    #pragma unroll
    for (int mt1 = 0; mt1 < 2; ++mt1)
        #pragma unroll
        for (int ksp = 0; ksp < 2; ++ksp) {
            wfb[mt1][ksp] = *(const bf16x8*)(bW1f + (((2 * w + mt1) * 2 + ksp) * 64 + l) * 8);
            wfu[mt1][ksp] = *(const bf16x8*)(uW1f + (((2 * w + mt1) * 2 + ksp) * 64 + l) * 8);
        }
    f32x4 b1v[2], ub1v[2];
    b1v[0]  = *(const f32x4*)(bb1 + 32 * w + 4 * g);
    b1v[1]  = *(const f32x4*)(bb1 + 32 * w + 16 + 4 * g);
    ub1v[0] = *(const f32x4*)(ub1 + 32 * w + 4 * g);
    ub1v[1] = *(const f32x4*)(ub1 + 32 * w + 16 + 4 * g);
    const float b3v = (c < 6) ? bb3[c] : 0.f;

    // ---- T-fragments in registers (element e -> k = 32*ks + 8*g + e); P row = c, Q row = c ----
    bf16x8 tP0, tP1, tQ0;
    {
        const bf16x8 z8 = {0,0,0,0,0,0,0,0};
        tP0 = z8; tP1 = z8; tQ0 = z8;
        union { unsigned u[4]; bf16x8 v; } U;
        if (g == 0) {
            const float* obp = cb + c * 6;
            const float2 a0 = *(const float2*)obp, a1 = *(const float2*)(obp + 2), a2v = *(const float2*)(obp + 4);
            U.u[0] = pkbf(a0.x, a0.y); U.u[1] = pkbf(a1.x, a1.y); U.u[2] = pkbf(a2v.x, a2v.y); U.u[3] = 0u;
            tP0 = U.v;                                   // k 0..5 = obj_i (i = c)
            const float4 b0 = *(const float4*)(ab + 20), b1q = *(const float4*)(ab + 24);
            U.u[0] = pkbf(b0.x, b0.y); U.u[1] = pkbf(b0.z, b0.w);
            U.u[2] = pkbf(b1q.x, b1q.y); U.u[3] = pkbf(b1q.z, b1q.w);
            tP1 = U.v;                                   // k 32..39 = action[20..27]
            U.u[0] = 0u; U.u[1] = 0u; U.u[2] = 0u; U.u[3] = pkbf(a0.x, a0.y);
            tQ0 = U.v;                                   // k 6,7 = obj_j[0,1] (j = c)
        } else if (g == 1) {
            const float4 b0 = *(const float4*)(ab + 0);
            U.u[0] = 0u; U.u[1] = 0u; U.u[2] = pkbf(b0.x, b0.y); U.u[3] = pkbf(b0.z, b0.w);
            tP0 = U.v;                                   // k 12..15 = action[0..3]
            const float4 b1q = *(const float4*)(ab + 28);
            U.u[0] = pkbf(b1q.x, b1q.y); U.u[1] = pkbf(b1q.z, b1q.w); U.u[2] = 0u; U.u[3] = 0u;
            tP1 = U.v;                                   // k 40..43 = action[28..31]
            const float* obq = cb + c * 6;
            const float2 q1 = *(const float2*)(obq + 2), q2 = *(const float2*)(obq + 4);
            U.u[0] = pkbf(q1.x, q1.y); U.u[1] = pkbf(q2.x, q2.y); U.u[2] = 0u; U.u[3] = 0u;
            tQ0 = U.v;                                   // k 8..11 = obj_j[2..5]
        } else if (g == 2) {
            const float4 b0 = *(const float4*)(ab + 4), b1q = *(const float4*)(ab + 8);
            U.u[0] = pkbf(b0.x, b0.y); U.u[1] = pkbf(b0.z, b0.w);
            U.u[2] = pkbf(b1q.x, b1q.y); U.u[3] = pkbf(b1q.z, b1q.w);
            tP0 = U.v;                                   // k 16..23 = action[4..11]
        } else {
            const float4 b0 = *(const float4*)(ab + 12), b1q = *(const float4*)(ab + 16);
            U.u[0] = pkbf(b0.x, b0.y); U.u[1] = pkbf(b0.z, b0.w);
            U.u[2] = pkbf(b1q.x, b1q.y); U.u[3] = pkbf(b1q.z, b1q.w);
            tP0 = U.v;                                   // k 24..31 = action[12..19]
        }
    }

    // ---- phase 1 (swapped): P'/Q/Pu = W1^T @ T^T; bias via acc init; 10 MFMAs ----
    {
        f32x4 acc1[2][2], accu[2];
        acc1[0][0] = b1v[0]; acc1[0][1] = zero4;
        acc1[1][0] = b1v[1]; acc1[1][1] = zero4;
        accu[0] = ub1v[0]; accu[1] = ub1v[1];
        #pragma unroll
        for (int mt1 = 0; mt1 < 2; ++mt1) {
            acc1[mt1][0] = __builtin_amdgcn_mfma_f32_16x16x32_bf16(wfb[mt1][0], tP0, acc1[mt1][0], 0, 0, 0);
            acc1[mt1][0] = __builtin_amdgcn_mfma_f32_16x16x32_bf16(wfb[mt1][1], tP1, acc1[mt1][0], 0, 0, 0);
            acc1[mt1][1] = __builtin_amdgcn_mfma_f32_16x16x32_bf16(wfb[mt1][0], tQ0, acc1[mt1][1], 0, 0, 0);
            accu[mt1]    = __builtin_amdgcn_mfma_f32_16x16x32_bf16(wfu[mt1][0], tP0, accu[mt1], 0, 0, 0);
            accu[mt1]    = __builtin_amdgcn_mfma_f32_16x16x32_bf16(wfu[mt1][1], tP1, accu[mt1], 0, 0, 0);
        }
        const int sw = (c & 7) << 4;
        #pragma unroll
        for (int mt1 = 0; mt1 < 2; ++mt1) {
            const int fb = (32 * w + 16 * mt1 + 4 * g) * 4;
            {   // P' row c (i = c)
                float2 v0; v0.x = acc1[mt1][0][0]; v0.y = acc1[mt1][0][1];
                float2 v1; v1.x = acc1[mt1][0][2]; v1.y = acc1[mt1][0][3];
                *(float2*)(PQs + ((c * 512 + fb)     ^ sw)) = v0;
                *(float2*)(PQs + ((c * 512 + fb + 8) ^ sw)) = v1;
            }
            {   // Q row 16 + c (j = c)
                float2 v0; v0.x = acc1[mt1][1][0]; v0.y = acc1[mt1][1][1];
                float2 v1; v1.x = acc1[mt1][1][2]; v1.y = acc1[mt1][1][3];
                *(float2*)(PQs + (((16 + c) * 512 + fb)     ^ sw)) = v0;
                *(float2*)(PQs + (((16 + c) * 512 + fb + 8) ^ sw)) = v1;
            }
            {   // Pu row c (i = c)
                float2 v0; v0.x = accu[mt1][0]; v0.y = accu[mt1][1];
                float2 v1; v1.x = accu[mt1][2]; v1.y = accu[mt1][3];
                *(float2*)(Pus + ((c * 512 + fb)     ^ sw)) = v0;
                *(float2*)(Pus + ((c * 512 + fb + 8) ^ sw)) = v1;
            }
        }
    }
    // ---- commit W2 stage to LDS (stride-16B lanes: conflict-free) ----
    {
        #pragma unroll
        for (int it = 0; it < 8; ++it)
            *(uint4*)(W2s + tid * 16 + it * 4096) = stg[it];
    }
    __syncthreads();

    // ---- phase 2: binary h1f[4][4] = relu(P'[4w+nt] + Q[c]); unary h1uf[4] = relu(Pu[c]) ----
    bf16x8 h1f[4][4], h1uf[4];
    {
        const int sw_c = (c & 7) << 4;
        #pragma unroll
        for (int ks = 0; ks < 4; ++ks) {
            const int kb = (32 * ks + 8 * g) * 4;
            const f32x4 q0 = *(const f32x4*)(PQs + (((16 + c) * 512 + kb)      ^ sw_c));
            const f32x4 q1 = *(const f32x4*)(PQs + (((16 + c) * 512 + kb + 16) ^ sw_c));
            const f32x4 u0 = *(const f32x4*)(Pus + ((c * 512 + kb)      ^ sw_c));
            const f32x4 u1 = *(const f32x4*)(Pus + ((c * 512 + kb + 16) ^ sw_c));
            union { unsigned u[4]; bf16x8 v; } uu;
            uu.u[0] = pkbf(fmaxf(u0[0], 0.f), fmaxf(u0[1], 0.f));
            uu.u[1] = pkbf(fmaxf(u0[2], 0.f), fmaxf(u0[3], 0.f));
            uu.u[2] = pkbf(fmaxf(u1[0], 0.f), fmaxf(u1[1], 0.f));
            uu.u[3] = pkbf(fmaxf(u1[2], 0.f), fmaxf(u1[3], 0.f));
            h1uf[ks] = uu.v;
            #pragma unroll
            for (int nt = 0; nt < 4; ++nt) {
                const int ip = 4 * w + nt;
                const f32x4 p0 = *(const f32x4*)(PQs + ((ip * 512 + kb)      ^ ((ip & 7) << 4)));
                const f32x4 p1 = *(const f32x4*)(PQs + ((ip * 512 + kb + 16) ^ ((ip & 7) << 4)));
                union { unsigned u[4]; bf16x8 v; } un;
                un.u[0] = pkbf(fmaxf(p0[0] + q0[0], 0.f), fmaxf(p0[1] + q0[1], 0.f));
                un.u[1] = pkbf(fmaxf(p0[2] + q0[2], 0.f), fmaxf(p0[3] + q0[3], 0.f));
                un.u[2] = pkbf(fmaxf(p1[0] + q1[0], 0.f), fmaxf(p1[1] + q1[1], 0.f));
                un.u[3] = pkbf(fmaxf(p1[2] + q1[2], 0.f), fmaxf(p1[3] + q1[3], 0.f));
                h1f[nt][ks] = un.v;
            }
        }
    }

    // ---- binary chunks: GEMM2 (W2 from LDS) -> relu-pack -> K=16 GEMM3 in registers ----
    f32x4 acc3[4];
    #pragma unroll
    for (int nt = 0; nt < 4; ++nt) { acc3[nt][0] = b3v; acc3[nt][1] = b3v; acc3[nt][2] = b3v; acc3[nt][3] = b3v; }
    #pragma unroll
    for (int ks = 0; ks < 4; ++ks) {
        bf16x8 wfa[8];
        #pragma unroll
        for (int q = 0; q < 8; ++q)   // q = mt1*4 + ksp
            wfa[q] = *(const bf16x8*)(W2s + ((2 * ks + (q >> 2)) * 4 + (q & 3)) * 1024 + l * 16);
        union { uint2 u2; bf16x4 v; } w3b[2];
        w3b[0].u2 = *(const uint2*)(bW3s + ((2 * ks)     * 64 + l) * 4);
        w3b[1].u2 = *(const uint2*)(bW3s + ((2 * ks + 1) * 64 + l) * 4);
        const f32x4 bv0 = *(const f32x4*)(bb2 + 32 * ks + 4 * g);
        const f32x4 bv1 = *(const f32x4*)(bb2 + 32 * ks + 16 + 4 * g);

        f32x4 a2[2][4];
        #pragma unroll
        for (int nt = 0; nt < 4; ++nt) { a2[0][nt] = bv0; a2[1][nt] = bv1; }
        #pragma unroll
        for (int ksp = 0; ksp < 4; ++ksp)
            #pragma unroll
            for (int mt1 = 0; mt1 < 2; ++mt1)
                #pragma unroll
                for (int nt = 0; nt < 4; ++nt)
                    a2[mt1][nt] = __builtin_amdgcn_mfma_f32_16x16x32_bf16(wfa[mt1 * 4 + ksp], h1f[nt][ksp], a2[mt1][nt], 0, 0, 0);
        #pragma unroll
        for (int mt1 = 0; mt1 < 2; ++mt1)
            #pragma unroll
            for (int nt = 0; nt < 4; ++nt) {
                union { unsigned u[2]; bf16x4 v; } pa;
                pa.u[0] = pkbf(fmaxf(a2[mt1][nt][0], 0.f), fmaxf(a2[mt1][nt][1], 0.f));
                pa.u[1] = pkbf(fmaxf(a2[mt1][nt][2], 0.f), fmaxf(a2[mt1][nt][3], 0.f));
                acc3[nt] = mfma16(pa.v, w3b[mt1].v, acc3[nt]);
            }
    }

    // ---- unary tail: wave w computes kappa-chunk w; partial out_u -> Psum ----
    {
        f32x4 a2u[2];
        a2u[0] = *(const f32x4*)(ub2 + 32 * w + 4 * g);
        a2u[1] = *(const f32x4*)(ub2 + 32 * w + 16 + 4 * g);
        #pragma unroll
        for (int ksp = 0; ksp < 4; ++ksp)
            #pragma unroll
            for (int mt1 = 0; mt1 < 2; ++mt1) {
                const bf16x8 wf = *(const bf16x8*)(uW2f + (((2 * w + mt1) * 4 + ksp) * 64 + l) * 8);
                a2u[mt1] = __builtin_amdgcn_mfma_f32_16x16x32_bf16(wf, h1uf[ksp], a2u[mt1], 0, 0, 0);
            }
        f32x4 acc3u = zero4;
        #pragma unroll
        for (int mt1 = 0; mt1 < 2; ++mt1) {
            union { uint2 u2; bf16x4 v; } w3u;
            w3u.u2 = *(const uint2*)(uW3s + ((2 * w + mt1) * 64 + l) * 4);
            union { unsigned u[2]; bf16x4 v; } pa;
            pa.u[0] = pkbf(fmaxf(a2u[mt1][0], 0.f), fmaxf(a2u[mt1][1], 0.f));
            pa.u[1] = pkbf(fmaxf(a2u[mt1][2], 0.f), fmaxf(a2u[mt1][3], 0.f));
            acc3u = mfma16(pa.v, w3u.v, acc3u);
        }
        #pragma unroll
        for (int r = 0; r < 4; ++r)
            Psum[w * 256 + (4 * g + r) * 16 + c] = acc3u[r];   // [w][i = 4g+r][n = c]
    }
    __syncthreads();

    // ---- epilogue: b_sum (mask diag, reduce over j) + unary reduce + single store ----
    #pragma unroll
    for (int nt = 0; nt < 4; ++nt) {
        const int i = 4 * w + nt;
        float s = 0.f;
        #pragma unroll
        for (int r = 0; r < 4; ++r) {
            const int j = 4 * g + r;
            if (j != i) s += acc3[nt][r];      // b3 already in accumulator (per-pair)
        }
        s += __shfl_xor(s, 16, 64);
        s += __shfl_xor(s, 32, 64);
        if (g == 0 && c < 6) {
            const float u = Psum[i * 16 + c] + Psum[256 + i * 16 + c]
                          + Psum[512 + i * 16 + c] + Psum[768 + i * 16 + c];
            out[b * 96 + i * 6 + c] = u + ub3[c] + cb[i * 6 + c] + s;
        }
    }
}

extern "C" void kernel_launch(void* const* d_in, const int* in_sizes, int n_in,
                              void* d_out, int out_size, void* d_ws, size_t ws_size,
                              hipStream_t stream) {
    const float* config = (const float*)d_in[0];
    const float* action = (const float*)d_in[1];
    const float* uW1 = (const float*)d_in[2];
    const float* ub1 = (const float*)d_in[3];
    const float* uW2 = (const float*)d_in[4];
    const float* ub2 = (const float*)d_in[5];
    const float* uW3 = (const float*)d_in[6];
    const float* ub3 = (const float*)d_in[7];
    const float* bW1 = (const float*)d_in[8];
    const float* bb1 = (const float*)d_in[9];
    const float* bW2 = (const float*)d_in[10];
    const float* bb2 = (const float*)d_in[11];
    const float* bW3 = (const float*)d_in[12];
    const float* bb3 = (const float*)d_in[13];
    float* out = (float*)d_out;

    unsigned short* ws    = (unsigned short*)d_ws;
    unsigned short* bW1f  = ws;            // 8192
    unsigned short* uW1f  = ws + 8192;     // 8192 (44-dim remapped)
    unsigned short* bW2f  = ws + 16384;    // 16384
    unsigned short* uW2f  = ws + 32768;    // 16384
    unsigned short* bW3s  = ws + 49152;    // 2048 (K=16 frags)
    unsigned short* uW3s  = ws + 51200;    // 2048 (K=16 frags)

    prep_all<<<208, 256, 0, stream>>>(uW1, uW2, uW3, bW1, bW2, bW3, ws);
    fused_kernel<<<4096, 256, 0, stream>>>(config, action,
                                           bW1f, bb1, uW1f, ub1,
                                           bW2f, bb2, uW2f, ub2,
                                           bW3s, bb3, uW3s, ub3, out);
}